// Round 4
// baseline (166.537 us; speedup 1.0000x reference)
//
#include <hip/hip_runtime.h>
#include <hip/hip_bf16.h>

// out[i,j] = alpha[i] * alpha[j] * A_hat[i,j]   (N x N, fp32)
// Memory-bound. Persistent blocks (grid-stride over rows), 16B vector I/O,
// nontemporal hints on the streaming 400MB+400MB A/out traffic.
// NOTE: __builtin_nontemporal_* requires a clang vector type, not HIP float4.

typedef float f32x4 __attribute__((ext_vector_type(4)));

__global__ __launch_bounds__(256) void stable_factor_kernel(
    const float* __restrict__ A,
    const float* __restrict__ alpha,
    float* __restrict__ out,
    int N, int nvec) {

    const f32x4* __restrict__ al4 = reinterpret_cast<const f32x4*>(alpha);

    for (int row = blockIdx.x; row < N; row += gridDim.x) {
        const float ai = alpha[row];                 // block-uniform -> scalar load
        const size_t off = (size_t)row * (size_t)N;
        const f32x4* __restrict__ A4 = reinterpret_cast<const f32x4*>(A + off);
        f32x4* __restrict__ O4       = reinterpret_cast<f32x4*>(out + off);

        for (int c = threadIdx.x; c < nvec; c += blockDim.x) {
            f32x4 a = __builtin_nontemporal_load(&A4[c]);   // streaming read
            f32x4 b = al4[c];                               // cached (40 KB total)
            f32x4 o = (ai * b) * a;
            __builtin_nontemporal_store(o, &O4[c]);         // streaming write
        }

        // generic tail if N % 4 != 0 (not hit for N=10000)
        for (int j = (nvec << 2) + threadIdx.x; j < N; j += blockDim.x) {
            out[off + j] = ai * alpha[j] * A[off + j];
        }
    }
}

extern "C" void kernel_launch(void* const* d_in, const int* in_sizes, int n_in,
                              void* d_out, int out_size, void* d_ws, size_t ws_size,
                              hipStream_t stream) {
    const float* A     = (const float*)d_in[0];   // A_hat, N*N fp32
    const float* alpha = (const float*)d_in[1];   // alpha, N fp32
    float* out         = (float*)d_out;

    const int N    = in_sizes[1];                 // 10000
    const int nvec = N >> 2;                      // 2500 float4 per row

    // 2048 blocks x 4 waves = 8192 waves = full chip capacity (256 CU x 32).
    dim3 block(256, 1, 1);
    dim3 grid(2048, 1, 1);
    stable_factor_kernel<<<grid, block, 0, stream>>>(A, alpha, out, N, nvec);
}

// Round 5
// 146.672 us; speedup vs baseline: 1.1354x; 1.1354x over previous
//
#include <hip/hip_runtime.h>
#include <hip/hip_bf16.h>

// out[i,j] = alpha[i] * alpha[j] * A_hat[i,j]   (N x N, fp32)
// Memory-bound. Each block: 8 rows x 256 float4 columns.
//  - alpha[j] quad loaded once, reused across 8 rows (kills redundant L1 traffic)
//  - 8 independent 16B loads in flight per thread (MLP), then 8 stores
//  - no nontemporal hints (R4 showed they regress: 146 -> 166 us)

typedef float f32x4 __attribute__((ext_vector_type(4)));

constexpr int ROWS = 8;

__global__ __launch_bounds__(256) void stable_factor_kernel(
    const float* __restrict__ A,
    const float* __restrict__ alpha,
    float* __restrict__ out,
    int N, int nvec) {

    const int c4 = blockIdx.x * blockDim.x + threadIdx.x;
    if (c4 >= nvec) return;

    const int row0 = blockIdx.y * ROWS;
    const f32x4 b = reinterpret_cast<const f32x4*>(alpha)[c4];   // reused 8x

    const f32x4* __restrict__ A4 = reinterpret_cast<const f32x4*>(A)   + (size_t)row0 * nvec + c4;
    f32x4*       __restrict__ O4 = reinterpret_cast<f32x4*>(out)       + (size_t)row0 * nvec + c4;

    if (row0 + ROWS <= N) {                      // fast path (always, N%8==0)
        float ai[ROWS];
        #pragma unroll
        for (int r = 0; r < ROWS; ++r) ai[r] = alpha[row0 + r];  // block-uniform scalar loads

        f32x4 a[ROWS];
        #pragma unroll
        for (int r = 0; r < ROWS; ++r) a[r] = A4[(size_t)r * nvec];  // 8 loads in flight

        #pragma unroll
        for (int r = 0; r < ROWS; ++r) O4[(size_t)r * nvec] = (ai[r] * b) * a[r];
    } else {                                     // generic tail rows
        for (int r = 0; r < ROWS && row0 + r < N; ++r) {
            f32x4 a = A4[(size_t)r * nvec];
            O4[(size_t)r * nvec] = (alpha[row0 + r] * b) * a;
        }
    }
}

extern "C" void kernel_launch(void* const* d_in, const int* in_sizes, int n_in,
                              void* d_out, int out_size, void* d_ws, size_t ws_size,
                              hipStream_t stream) {
    const float* A     = (const float*)d_in[0];   // A_hat, N*N fp32
    const float* alpha = (const float*)d_in[1];   // alpha, N fp32
    float* out         = (float*)d_out;

    const int N    = in_sizes[1];                 // 10000
    const int nvec = N >> 2;                      // 2500 float4 per row

    dim3 block(256, 1, 1);
    dim3 grid((nvec + 255) / 256, (N + ROWS - 1) / ROWS, 1);   // (10, 1250)
    stable_factor_kernel<<<grid, block, 0, stream>>>(A, alpha, out, N, nvec);
}

// Round 6
// 139.579 us; speedup vs baseline: 1.1931x; 1.0508x over previous
//
#include <hip/hip_runtime.h>
#include <hip/hip_bf16.h>

// out[i,j] = alpha[i] * alpha[j] * A_hat[i,j]   (N x N, fp32)
// Memory-bound. Identical structure to R5 (8 rows x 256 float4 per block,
// alpha-quad reuse, 8 loads in flight) with ONE change: nontemporal STORE
// (evict-first in L2) so the 400MB output stream doesn't evict A's read
// lines from the 32MB L2. Loads stay plain (R4 suggested nt-load hurts).

typedef float f32x4 __attribute__((ext_vector_type(4)));

constexpr int ROWS = 8;

__global__ __launch_bounds__(256) void stable_factor_kernel(
    const float* __restrict__ A,
    const float* __restrict__ alpha,
    float* __restrict__ out,
    int N, int nvec) {

    const int c4 = blockIdx.x * blockDim.x + threadIdx.x;
    if (c4 >= nvec) return;

    const int row0 = blockIdx.y * ROWS;
    const f32x4 b = reinterpret_cast<const f32x4*>(alpha)[c4];   // reused 8x

    const f32x4* __restrict__ A4 = reinterpret_cast<const f32x4*>(A)   + (size_t)row0 * nvec + c4;
    f32x4*       __restrict__ O4 = reinterpret_cast<f32x4*>(out)       + (size_t)row0 * nvec + c4;

    if (row0 + ROWS <= N) {                      // fast path (always, N%8==0)
        float ai[ROWS];
        #pragma unroll
        for (int r = 0; r < ROWS; ++r) ai[r] = alpha[row0 + r];  // block-uniform scalar loads

        f32x4 a[ROWS];
        #pragma unroll
        for (int r = 0; r < ROWS; ++r) a[r] = A4[(size_t)r * nvec];  // 8 loads in flight

        #pragma unroll
        for (int r = 0; r < ROWS; ++r) {
            f32x4 o = (ai[r] * b) * a[r];
            __builtin_nontemporal_store(o, &O4[(size_t)r * nvec]);   // evict-first write
        }
    } else {                                     // generic tail rows
        for (int r = 0; r < ROWS && row0 + r < N; ++r) {
            f32x4 a = A4[(size_t)r * nvec];
            f32x4 o = (alpha[row0 + r] * b) * a;
            __builtin_nontemporal_store(o, &O4[(size_t)r * nvec]);
        }
    }
}

extern "C" void kernel_launch(void* const* d_in, const int* in_sizes, int n_in,
                              void* d_out, int out_size, void* d_ws, size_t ws_size,
                              hipStream_t stream) {
    const float* A     = (const float*)d_in[0];   // A_hat, N*N fp32
    const float* alpha = (const float*)d_in[1];   // alpha, N fp32
    float* out         = (float*)d_out;

    const int N    = in_sizes[1];                 // 10000
    const int nvec = N >> 2;                      // 2500 float4 per row

    dim3 block(256, 1, 1);
    dim3 grid((nvec + 255) / 256, (N + ROWS - 1) / ROWS, 1);   // (10, 1250)
    stable_factor_kernel<<<grid, block, 0, stream>>>(A, alpha, out, N, nvec);
}

// Round 7
// 133.709 us; speedup vs baseline: 1.2455x; 1.0439x over previous
//
#include <hip/hip_runtime.h>
#include <hip/hip_bf16.h>

// out[i,j] = alpha[i] * alpha[j] * A_hat[i,j]   (N x N, fp32)
// Memory-bound. Identical to R6 (8 rows x 256 float4 per block, alpha-quad
// reuse, nt-store) with ONE change: nontemporal LOAD on the A stream too.
// A is never re-read -> L2 residency for it is worthless; nt on both
// streams makes L2 a pass-through for the 800MB streaming traffic.

typedef float f32x4 __attribute__((ext_vector_type(4)));

constexpr int ROWS = 8;

__global__ __launch_bounds__(256) void stable_factor_kernel(
    const float* __restrict__ A,
    const float* __restrict__ alpha,
    float* __restrict__ out,
    int N, int nvec) {

    const int c4 = blockIdx.x * blockDim.x + threadIdx.x;
    if (c4 >= nvec) return;

    const int row0 = blockIdx.y * ROWS;
    const f32x4 b = reinterpret_cast<const f32x4*>(alpha)[c4];   // reused 8x

    const f32x4* __restrict__ A4 = reinterpret_cast<const f32x4*>(A)   + (size_t)row0 * nvec + c4;
    f32x4*       __restrict__ O4 = reinterpret_cast<f32x4*>(out)       + (size_t)row0 * nvec + c4;

    if (row0 + ROWS <= N) {                      // fast path (always, N%8==0)
        float ai[ROWS];
        #pragma unroll
        for (int r = 0; r < ROWS; ++r) ai[r] = alpha[row0 + r];  // block-uniform scalar loads

        f32x4 a[ROWS];
        #pragma unroll
        for (int r = 0; r < ROWS; ++r)
            a[r] = __builtin_nontemporal_load(&A4[(size_t)r * nvec]);  // streaming read

        #pragma unroll
        for (int r = 0; r < ROWS; ++r) {
            f32x4 o = (ai[r] * b) * a[r];
            __builtin_nontemporal_store(o, &O4[(size_t)r * nvec]);     // streaming write
        }
    } else {                                     // generic tail rows
        for (int r = 0; r < ROWS && row0 + r < N; ++r) {
            f32x4 a = __builtin_nontemporal_load(&A4[(size_t)r * nvec]);
            f32x4 o = (alpha[row0 + r] * b) * a;
            __builtin_nontemporal_store(o, &O4[(size_t)r * nvec]);
        }
    }
}

extern "C" void kernel_launch(void* const* d_in, const int* in_sizes, int n_in,
                              void* d_out, int out_size, void* d_ws, size_t ws_size,
                              hipStream_t stream) {
    const float* A     = (const float*)d_in[0];   // A_hat, N*N fp32
    const float* alpha = (const float*)d_in[1];   // alpha, N fp32
    float* out         = (float*)d_out;

    const int N    = in_sizes[1];                 // 10000
    const int nvec = N >> 2;                      // 2500 float4 per row

    dim3 block(256, 1, 1);
    dim3 grid((nvec + 255) / 256, (N + ROWS - 1) / ROWS, 1);   // (10, 1250)
    stable_factor_kernel<<<grid, block, 0, stream>>>(A, alpha, out, N, nvec);
}